// Round 5
// baseline (234.168 us; speedup 1.0000x reference)
//
#include <hip/hip_runtime.h>
#include <hip/hip_bf16.h>

// Problem constants (B=4, H=16, S=2048, D=64, N=2048, T=8)
constexpr int B  = 4;
constexpr int H  = 16;
constexpr int S  = 2048;
constexpr int D  = 64;
constexpr int BH = B * H;

constexpr float ANG   = 1.5707963267948966f / 2048.0f;  // (pi/2)/N
constexpr float INV_T = 0.125f;

typedef __attribute__((ext_vector_type(8))) short bf16x8v;  // MFMA A/B frag
typedef __attribute__((ext_vector_type(4))) short s16x4;    // 4 bf16 (8 B)
typedef __attribute__((ext_vector_type(4))) float f32x4;    // MFMA acc

__device__ __forceinline__ short f2bf(float f) {
    __hip_bfloat16 h = __float2bfloat16(f);
    return __builtin_bit_cast(short, h);
}
__device__ __forceinline__ float bf2f(short u) {
    return __bfloat162float(__builtin_bit_cast(__hip_bfloat16, u));
}
__device__ __forceinline__ float non_neg(float x) {
    return x < 0.0f ? __expf(x) : x + 1.0f;
}
__device__ __forceinline__ bf16x8v comb(s16x4 lo, s16x4 hi) {
    return __builtin_shufflevector(lo, hi, 0, 1, 2, 3, 4, 5, 6, 7);
}

#define MFMA16 __builtin_amdgcn_mfma_f32_16x16x32_bf16

constexpr int PADS = 36;  // padded s-stride (shorts): 72 B rows, 8 B aligned

// ---------------------------------------------------------------------------
// Pass 1 (+ fused split-K reduce): per (ck,bh) block accumulates
//   partial = sum_{s in chunk} fk(s,dk)*{cos,sin}(s)*V(s,dv)   (bf16 store)
// then the LAST block per bh (device-scope ticket) sums all chunks and emits
// M in pass2's B-fragment layout (bf16).
// Transpose on the GLOBAL side: lane = dk column, wave walks 8 s-rows with
// coalesced dword loads; aligned b64 stores into transposed LDS [plane][d][s];
// fragment reads contiguous b64. Double-buffered, issue-early/write-late.
// 4 waves: wave wv owns dk-slice [wv*16, wv*16+16); disjoint outputs.
// ---------------------------------------------------------------------------
__global__ __launch_bounds__(256, 4) void lin_attn_pass1(
        const float* __restrict__ K, const float* __restrict__ V,
        short* __restrict__ partial, short* __restrict__ Mtb,
        int* __restrict__ cnt, int s_chunk) {
    const int bh = blockIdx.y, ck = blockIdx.x, nc = gridDim.x;
    const int t = threadIdx.x, wave = t >> 6, lane = t & 63;
    const int h = lane >> 4, c = lane & 15;
    const int sb = ck * s_chunk, ntiles = s_chunk / 32;

    const float* __restrict__ kb = K + (size_t)bh * S * D;
    const float* __restrict__ vb = V + (size_t)bh * S * D;

    // [buf][plane kc/ks/v][d][s(padded)] bf16
    __shared__ short lds[2][3][D][PADS];

    f32x4 accC[4], accS[4];
    const f32x4 z4 = {0.f, 0.f, 0.f, 0.f};
    #pragma unroll
    for (int i = 0; i < 4; ++i) { accC[i] = z4; accS[i] = z4; }

    auto loadt = [&](int tile, float* kv, float* vv) {
        const float* __restrict__ kp =
            kb + (size_t)(sb + tile * 32 + 8 * wave) * D + lane;
        const float* __restrict__ vp =
            vb + (size_t)(sb + tile * 32 + 8 * wave) * D + lane;
        #pragma unroll
        for (int i = 0; i < 8; ++i) {          // 8 coalesced 256B row reads
            kv[i] = kp[(size_t)i * D];
            vv[i] = vp[(size_t)i * D];
        }
    };
    auto stagew = [&](int buf, int tile, const float* kv, const float* vv) {
        s16x4 kcq[2], ksq[2], vq[2];
        #pragma unroll
        for (int i = 0; i < 8; ++i) {
            const int s = sb + tile * 32 + 8 * wave + i;
            float sn, cs;
            __sincosf(ANG * (float)s, &sn, &cs);
            const float fk = non_neg(kv[i]);
            kcq[i >> 2][i & 3] = f2bf(fk * cs);
            ksq[i >> 2][i & 3] = f2bf(fk * sn);
            vq [i >> 2][i & 3] = f2bf(vv[i]);
        }
        #pragma unroll
        for (int hf = 0; hf < 2; ++hf) {       // aligned 8B stores, transposed
            *(s16x4*)&lds[buf][0][lane][8 * wave + 4 * hf] = kcq[hf];
            *(s16x4*)&lds[buf][1][lane][8 * wave + 4 * hf] = ksq[hf];
            *(s16x4*)&lds[buf][2][lane][8 * wave + 4 * hf] = vq[hf];
        }
    };

    float kv[8], vv[8], kn[8], vn[8];
    loadt(0, kv, vv);
    stagew(0, 0, kv, vv);
    __syncthreads();

    for (int tt = 0; tt < ntiles; ++tt) {
        const int cur = tt & 1;
        const bool pf = (tt + 1 < ntiles);
        if (pf) loadt(tt + 1, kn, vn);         // issue early (T14)

        // A-frags: lane (h,c) row dk = wave*16+c, k-slots s = 8h..8h+7
        const int arow = wave * 16 + c;
        const bf16x8v kcF = comb(*(const s16x4*)&lds[cur][0][arow][8 * h],
                                 *(const s16x4*)&lds[cur][0][arow][8 * h + 4]);
        const bf16x8v ksF = comb(*(const s16x4*)&lds[cur][1][arow][8 * h],
                                 *(const s16x4*)&lds[cur][1][arow][8 * h + 4]);
        #pragma unroll
        for (int tdv = 0; tdv < 4; ++tdv) {
            const int brow = tdv * 16 + c;     // col dv, same k-slot mapping
            const bf16x8v vF =
                comb(*(const s16x4*)&lds[cur][2][brow][8 * h],
                     *(const s16x4*)&lds[cur][2][brow][8 * h + 4]);
            accC[tdv] = MFMA16(kcF, vF, accC[tdv], 0, 0, 0);
            accS[tdv] = MFMA16(ksF, vF, accS[tdv], 0, 0, 0);
        }

        if (pf) stagew(cur ^ 1, tt + 1, kn, vn);  // write late
        __syncthreads();
    }

    // store this block's [2][64][64] partial in bf16 (C/D: row=4h+r, col=c)
    short* __restrict__ dst = partial + ((size_t)ck * BH + bh) * 8192;
    #pragma unroll
    for (int tdv = 0; tdv < 4; ++tdv)
        #pragma unroll
        for (int r = 0; r < 4; ++r) {
            const int dk = wave * 16 + 4 * h + r;
            dst[dk * 64 + tdv * 16 + c]        = f2bf(accC[tdv][r]);
            dst[4096 + dk * 64 + tdv * 16 + c] = f2bf(accS[tdv][r]);
        }

    // --- split-K ticket: last block per bh reduces all chunks -> Mtb ---
    __shared__ int isLast;
    __threadfence();                            // release partial stores
    __syncthreads();
    if (t == 0) isLast = (atomicAdd(&cnt[bh], 1) == nc - 1);
    __syncthreads();
    if (!isLast) return;
    __threadfence();                            // acquire others' partials

    const short* __restrict__ pb = partial + (size_t)bh * 8192;
    short* __restrict__ mout = Mtb + (size_t)bh * 8192;
    #pragma unroll
    for (int i = 0; i < 8; ++i) {
        const int e4 = t + i * 256;             // short4 index, e = 4*e4+j
        float s0 = 0.f, s1 = 0.f, s2 = 0.f, s3 = 0.f;
        for (int c2 = 0; c2 < nc; ++c2) {
            const s16x4 p =
                *(const s16x4*)(pb + (size_t)c2 * BH * 8192 + e4 * 4);
            s0 += bf2f(p[0]); s1 += bf2f(p[1]); s2 += bf2f(p[2]); s3 += bf2f(p[3]);
        }
        const float sv[4] = {s0, s1, s2, s3};
        #pragma unroll
        for (int j = 0; j < 4; ++j) {
            const int e  = e4 * 4 + j;
            const int m  = e >> 12, dk = (e >> 6) & 63, dv = e & 63;
            const int kk = dk >> 5, h2 = (dk >> 3) & 3, i2 = dk & 7;
            const int dt = dv >> 4, c3 = dv & 15;
            mout[((m * 2 + kk) * 4 + dt) * 512 + (h2 * 16 + c3) * 8 + i2] =
                f2bf(sv[j]);
        }
    }
}

// ---------------------------------------------------------------------------
// Pass 2: out = cos*(Fq·Mc) + sin*(Fq·Ms), Fq = non_neg(q)*mask/T.
// B-frags loaded once (fragment layout, 1 dwordx4/lane). A staged per s-tile
// in wave-private XOR-swizzled bf16 LDS. cos/sin applied in f32 epilogue.
// grid (16, BH): wave owns 32 s-rows (2 tiles), q prefetched one tile ahead.
// ---------------------------------------------------------------------------
__global__ __launch_bounds__(256) void lin_attn_pass2(
        const float* __restrict__ Q, const int* __restrict__ mask,
        const short* __restrict__ Mtb, float* __restrict__ out) {
    const int bh = blockIdx.y, b = bh >> 4;
    const int t = threadIdx.x, wave = t >> 6, lane = t & 63;
    const int h = lane >> 4, c = lane & 15;
    const int s_base = blockIdx.x * 128 + wave * 32;

    const float* __restrict__ qb = Q + (size_t)bh * S * D;
    float* __restrict__ ob = out + (size_t)bh * S * D;
    const short* __restrict__ mb = Mtb + (size_t)bh * 8192;

    bf16x8v bF[16];
    #pragma unroll
    for (int i = 0; i < 16; ++i)
        bF[i] = *(const bf16x8v*)(mb + i * 512 + lane * 8);

    __shared__ __align__(16) short qlds[4][1024];  // 2 KB per wave, private
    short* ql = qlds[wave];

    float4 qv[4], qn[4];
    #pragma unroll
    for (int i = 0; i < 4; ++i)
        qv[i] = *(const float4*)(qb + (size_t)(s_base + 4 * i + h) * D + 4 * c);

    #pragma unroll
    for (int st = 0; st < 2; ++st) {
        if (st < 1) {
            #pragma unroll
            for (int i = 0; i < 4; ++i)
                qn[i] = *(const float4*)(
                    qb + (size_t)(s_base + 16 + 4 * i + h) * D + 4 * c);
        }
        const int s0 = s_base + st * 16;

        // stage Fq tile (mask & 1/T baked; XOR-swizzled cols)
        #pragma unroll
        for (int i = 0; i < 4; ++i) {
            const int row = 4 * i + h;
            const float mv = mask[(size_t)b * S + s0 + row] ? INV_T : 0.f;
            s16x4 p = {f2bf(non_neg(qv[i].x) * mv), f2bf(non_neg(qv[i].y) * mv),
                       f2bf(non_neg(qv[i].z) * mv), f2bf(non_neg(qv[i].w) * mv)};
            *(s16x4*)&ql[row * 64 + ((4 * c) ^ ((row & 7) << 3))] = p;
        }

        f32x4 aC[4], aS[4];
        const f32x4 z4 = {0.f, 0.f, 0.f, 0.f};
        #pragma unroll
        for (int i = 0; i < 4; ++i) { aC[i] = z4; aS[i] = z4; }

        #pragma unroll
        for (int kk = 0; kk < 2; ++kk) {
            const bf16x8v aF =
                *(const bf16x8v*)&ql[c * 64 + ((kk * 32 + 8 * h) ^ ((c & 7) << 3))];
            #pragma unroll
            for (int dt = 0; dt < 4; ++dt) {
                aC[dt] = MFMA16(aF, bF[kk * 4 + dt], aC[dt], 0, 0, 0);
                aS[dt] = MFMA16(aF, bF[8 + kk * 4 + dt], aS[dt], 0, 0, 0);
            }
        }

        #pragma unroll
        for (int r = 0; r < 4; ++r) {
            const int srow = s0 + 4 * h + r;
            float sn, cs;
            __sincosf(ANG * (float)srow, &sn, &cs);
            #pragma unroll
            for (int dt = 0; dt < 4; ++dt)
                ob[(size_t)srow * D + dt * 16 + c] = cs * aC[dt][r] + sn * aS[dt][r];
        }
        if (st < 1) {
            #pragma unroll
            for (int i = 0; i < 4; ++i) qv[i] = qn[i];
        }
    }
}

// ---------------------------------------------------------------------------
extern "C" void kernel_launch(void* const* d_in, const int* in_sizes, int n_in,
                              void* d_out, int out_size, void* d_ws, size_t ws_size,
                              hipStream_t stream) {
    const float* q    = (const float*)d_in[0];
    const float* k    = (const float*)d_in[1];
    const float* v    = (const float*)d_in[2];
    const int*   mask = (const int*)d_in[3];
    float*       out  = (float*)d_out;

    // ws layout: [cnt: 1 KB][Mtb: 1 MB][partial: nc MB (bf16)]
    int*   cnt     = (int*)d_ws;
    short* Mtb     = (short*)((char*)d_ws + 1024);
    short* partial = (short*)((char*)d_ws + 1024 + (size_t)BH * 8192 * sizeof(short));

    auto fits = [&](int n) {
        return 1024 + (size_t)(n + 1) * BH * 8192 * sizeof(short) <= ws_size;
    };
    const int nc = fits(16) ? 16 : (fits(8) ? 8 : (fits(4) ? 4 : 1));

    hipMemsetAsync(cnt, 0, BH * sizeof(int), stream);
    lin_attn_pass1<<<dim3(nc, BH), dim3(256), 0, stream>>>(
        k, v, partial, Mtb, cnt, S / nc);
    lin_attn_pass2<<<dim3(16, BH), dim3(256), 0, stream>>>(q, mask, Mtb, out);
}

// Round 6
// 34.087 us; speedup vs baseline: 6.8696x; 6.8696x over previous
//
#include <hip/hip_runtime.h>
#include <hip/hip_bf16.h>

// Problem constants (B=4, H=16, S=2048, D=64, N=2048, T=8)
constexpr int B  = 4;
constexpr int H  = 16;
constexpr int S  = 2048;
constexpr int D  = 64;
constexpr int BH = B * H;

constexpr float ANG   = 1.5707963267948966f / 2048.0f;  // (pi/2)/N
constexpr float INV_T = 0.125f;

typedef __attribute__((ext_vector_type(8))) short bf16x8v;  // MFMA A/B frag
typedef __attribute__((ext_vector_type(4))) short s16x4;    // 4 bf16 (8 B)
typedef __attribute__((ext_vector_type(4))) float f32x4;    // MFMA acc

__device__ __forceinline__ short f2bf(float f) {
    __hip_bfloat16 h = __float2bfloat16(f);
    return __builtin_bit_cast(short, h);
}
__device__ __forceinline__ float bf2f(short u) {
    return __bfloat162float(__builtin_bit_cast(__hip_bfloat16, u));
}
__device__ __forceinline__ float non_neg(float x) {
    return x < 0.0f ? __expf(x) : x + 1.0f;
}
__device__ __forceinline__ bf16x8v comb(s16x4 lo, s16x4 hi) {
    return __builtin_shufflevector(lo, hi, 0, 1, 2, 3, 4, 5, 6, 7);
}

#define MFMA16 __builtin_amdgcn_mfma_f32_16x16x32_bf16

constexpr int PADS = 36;  // padded s-stride (shorts): 72 B rows, 8 B aligned

// ---------------------------------------------------------------------------
// Pass 1: partial[ck][bh][m][dk][dv] = sum_{s in chunk} fk(s,dk)*{cos,sin}(s)*V(s,dv)
// (bf16 partial store). Transpose on the GLOBAL side: lane = dk column, wave
// walks 8 s-rows with coalesced dword loads; aligned b64 stores into
// transposed LDS [plane][d][s]; fragment reads contiguous b64. Double-
// buffered, issue-early/write-late. 4 waves: wave wv owns dk-slice
// [wv*16, wv*16+16); disjoint outputs. NO fused reduce tail (round-5 lesson:
// tail register pressure spilled the main-loop arrays to scratch).
// ---------------------------------------------------------------------------
__global__ __launch_bounds__(256, 4) void lin_attn_pass1(
        const float* __restrict__ K, const float* __restrict__ V,
        short* __restrict__ partial, int s_chunk) {
    const int bh = blockIdx.y, ck = blockIdx.x;
    const int t = threadIdx.x, wave = t >> 6, lane = t & 63;
    const int h = lane >> 4, c = lane & 15;
    const int sb = ck * s_chunk, ntiles = s_chunk / 32;

    const float* __restrict__ kb = K + (size_t)bh * S * D;
    const float* __restrict__ vb = V + (size_t)bh * S * D;

    // [buf][plane kc/ks/v][d][s(padded)] bf16
    __shared__ short lds[2][3][D][PADS];

    f32x4 accC[4], accS[4];
    const f32x4 z4 = {0.f, 0.f, 0.f, 0.f};
    #pragma unroll
    for (int i = 0; i < 4; ++i) { accC[i] = z4; accS[i] = z4; }

    auto loadt = [&](int tile, float* kv, float* vv) {
        const float* __restrict__ kp =
            kb + (size_t)(sb + tile * 32 + 8 * wave) * D + lane;
        const float* __restrict__ vp =
            vb + (size_t)(sb + tile * 32 + 8 * wave) * D + lane;
        #pragma unroll
        for (int i = 0; i < 8; ++i) {          // 8 coalesced 256B row reads
            kv[i] = kp[(size_t)i * D];
            vv[i] = vp[(size_t)i * D];
        }
    };
    auto stagew = [&](int buf, int tile, const float* kv, const float* vv) {
        s16x4 kcq[2], ksq[2], vq[2];
        #pragma unroll
        for (int i = 0; i < 8; ++i) {
            const int s = sb + tile * 32 + 8 * wave + i;
            float sn, cs;
            __sincosf(ANG * (float)s, &sn, &cs);
            const float fk = non_neg(kv[i]);
            kcq[i >> 2][i & 3] = f2bf(fk * cs);
            ksq[i >> 2][i & 3] = f2bf(fk * sn);
            vq [i >> 2][i & 3] = f2bf(vv[i]);
        }
        #pragma unroll
        for (int hf = 0; hf < 2; ++hf) {       // aligned 8B stores, transposed
            *(s16x4*)&lds[buf][0][lane][8 * wave + 4 * hf] = kcq[hf];
            *(s16x4*)&lds[buf][1][lane][8 * wave + 4 * hf] = ksq[hf];
            *(s16x4*)&lds[buf][2][lane][8 * wave + 4 * hf] = vq[hf];
        }
    };

    float kv[8], vv[8], kn[8], vn[8];
    loadt(0, kv, vv);
    stagew(0, 0, kv, vv);
    __syncthreads();

    for (int tt = 0; tt < ntiles; ++tt) {
        const int cur = tt & 1;
        const bool pf = (tt + 1 < ntiles);
        if (pf) loadt(tt + 1, kn, vn);         // issue early (T14)

        // A-frags: lane (h,c) row dk = wave*16+c, k-slots s = 8h..8h+7
        const int arow = wave * 16 + c;
        const bf16x8v kcF = comb(*(const s16x4*)&lds[cur][0][arow][8 * h],
                                 *(const s16x4*)&lds[cur][0][arow][8 * h + 4]);
        const bf16x8v ksF = comb(*(const s16x4*)&lds[cur][1][arow][8 * h],
                                 *(const s16x4*)&lds[cur][1][arow][8 * h + 4]);
        #pragma unroll
        for (int tdv = 0; tdv < 4; ++tdv) {
            const int brow = tdv * 16 + c;     // col dv, same k-slot mapping
            const bf16x8v vF =
                comb(*(const s16x4*)&lds[cur][2][brow][8 * h],
                     *(const s16x4*)&lds[cur][2][brow][8 * h + 4]);
            accC[tdv] = MFMA16(kcF, vF, accC[tdv], 0, 0, 0);
            accS[tdv] = MFMA16(ksF, vF, accS[tdv], 0, 0, 0);
        }

        if (pf) stagew(cur ^ 1, tt + 1, kn, vn);  // write late
        __syncthreads();
    }

    // store this block's [2][64][64] partial in bf16 (C/D: row=4h+r, col=c)
    short* __restrict__ dst = partial + ((size_t)ck * BH + bh) * 8192;
    #pragma unroll
    for (int tdv = 0; tdv < 4; ++tdv)
        #pragma unroll
        for (int r = 0; r < 4; ++r) {
            const int dk = wave * 16 + 4 * h + r;
            dst[dk * 64 + tdv * 16 + c]        = f2bf(accC[tdv][r]);
            dst[4096 + dk * 64 + tdv * 16 + c] = f2bf(accS[tdv][r]);
        }
}

// ---------------------------------------------------------------------------
// Reduce: sum bf16 chunk partials (s16x4 loads, 4 elems/thread), emit M in
// pass2's B-FRAGMENT layout (bf16):
// Mtb[bh][(m*2+kk)*4+dt][lane=(h*16+c)][i]; pass2 loads 16B/lane coalesced.
// grid (8, BH), 256 thr.
// ---------------------------------------------------------------------------
__global__ __launch_bounds__(256) void lin_attn_reduce(
        const short* __restrict__ partial, short* __restrict__ Mtb, int nc) {
    const int bh = blockIdx.y;
    const int e4 = blockIdx.x * 256 + threadIdx.x;   // 0..2047 (4 elems each)
    const short* __restrict__ pb = partial + (size_t)bh * 8192 + e4 * 4;

    float s0 = 0.f, s1 = 0.f, s2 = 0.f, s3 = 0.f;
    for (int c2 = 0; c2 < nc; ++c2) {
        const s16x4 p = *(const s16x4*)(pb + (size_t)c2 * BH * 8192);
        s0 += bf2f(p[0]); s1 += bf2f(p[1]); s2 += bf2f(p[2]); s3 += bf2f(p[3]);
    }
    const float sv[4] = {s0, s1, s2, s3};

    short* __restrict__ mout = Mtb + (size_t)bh * 8192;
    #pragma unroll
    for (int j = 0; j < 4; ++j) {
        const int e  = e4 * 4 + j;               // [m][dk][dv] linear
        const int m  = e >> 12, dk = (e >> 6) & 63, dv = e & 63;
        const int kk = dk >> 5, h2 = (dk >> 3) & 3, i2 = dk & 7;
        const int dt = dv >> 4, c3 = dv & 15;
        mout[((m * 2 + kk) * 4 + dt) * 512 + (h2 * 16 + c3) * 8 + i2] = f2bf(sv[j]);
    }
}

// ---------------------------------------------------------------------------
// Pass 2: out = cos*(Fq·Mc) + sin*(Fq·Ms), Fq = non_neg(q)*mask/T.
// B-frags loaded once (fragment layout, 1 dwordx4/lane). A staged per s-tile
// in wave-private XOR-swizzled bf16 LDS. cos/sin applied in f32 epilogue.
// grid (16, BH): wave owns 32 s-rows (2 tiles), q prefetched one tile ahead.
// ---------------------------------------------------------------------------
__global__ __launch_bounds__(256) void lin_attn_pass2(
        const float* __restrict__ Q, const int* __restrict__ mask,
        const short* __restrict__ Mtb, float* __restrict__ out) {
    const int bh = blockIdx.y, b = bh >> 4;
    const int t = threadIdx.x, wave = t >> 6, lane = t & 63;
    const int h = lane >> 4, c = lane & 15;
    const int s_base = blockIdx.x * 128 + wave * 32;

    const float* __restrict__ qb = Q + (size_t)bh * S * D;
    float* __restrict__ ob = out + (size_t)bh * S * D;
    const short* __restrict__ mb = Mtb + (size_t)bh * 8192;

    bf16x8v bF[16];
    #pragma unroll
    for (int i = 0; i < 16; ++i)
        bF[i] = *(const bf16x8v*)(mb + i * 512 + lane * 8);

    __shared__ __align__(16) short qlds[4][1024];  // 2 KB per wave, private
    short* ql = qlds[wave];

    float4 qv[4], qn[4];
    #pragma unroll
    for (int i = 0; i < 4; ++i)
        qv[i] = *(const float4*)(qb + (size_t)(s_base + 4 * i + h) * D + 4 * c);

    #pragma unroll
    for (int st = 0; st < 2; ++st) {
        if (st < 1) {
            #pragma unroll
            for (int i = 0; i < 4; ++i)
                qn[i] = *(const float4*)(
                    qb + (size_t)(s_base + 16 + 4 * i + h) * D + 4 * c);
        }
        const int s0 = s_base + st * 16;

        // stage Fq tile (mask & 1/T baked; XOR-swizzled cols)
        #pragma unroll
        for (int i = 0; i < 4; ++i) {
            const int row = 4 * i + h;
            const float mv = mask[(size_t)b * S + s0 + row] ? INV_T : 0.f;
            s16x4 p = {f2bf(non_neg(qv[i].x) * mv), f2bf(non_neg(qv[i].y) * mv),
                       f2bf(non_neg(qv[i].z) * mv), f2bf(non_neg(qv[i].w) * mv)};
            *(s16x4*)&ql[row * 64 + ((4 * c) ^ ((row & 7) << 3))] = p;
        }

        f32x4 aC[4], aS[4];
        const f32x4 z4 = {0.f, 0.f, 0.f, 0.f};
        #pragma unroll
        for (int i = 0; i < 4; ++i) { aC[i] = z4; aS[i] = z4; }

        #pragma unroll
        for (int kk = 0; kk < 2; ++kk) {
            const bf16x8v aF =
                *(const bf16x8v*)&ql[c * 64 + ((kk * 32 + 8 * h) ^ ((c & 7) << 3))];
            #pragma unroll
            for (int dt = 0; dt < 4; ++dt) {
                aC[dt] = MFMA16(aF, bF[kk * 4 + dt], aC[dt], 0, 0, 0);
                aS[dt] = MFMA16(aF, bF[8 + kk * 4 + dt], aS[dt], 0, 0, 0);
            }
        }

        #pragma unroll
        for (int r = 0; r < 4; ++r) {
            const int srow = s0 + 4 * h + r;
            float sn, cs;
            __sincosf(ANG * (float)srow, &sn, &cs);
            #pragma unroll
            for (int dt = 0; dt < 4; ++dt)
                ob[(size_t)srow * D + dt * 16 + c] = cs * aC[dt][r] + sn * aS[dt][r];
        }
        if (st < 1) {
            #pragma unroll
            for (int i = 0; i < 4; ++i) qv[i] = qn[i];
        }
    }
}

// ---------------------------------------------------------------------------
extern "C" void kernel_launch(void* const* d_in, const int* in_sizes, int n_in,
                              void* d_out, int out_size, void* d_ws, size_t ws_size,
                              hipStream_t stream) {
    const float* q    = (const float*)d_in[0];
    const float* k    = (const float*)d_in[1];
    const float* v    = (const float*)d_in[2];
    const int*   mask = (const int*)d_in[3];
    float*       out  = (float*)d_out;

    // ws layout: [Mtb: 1 MB][partial: nc MB (bf16)]
    short* Mtb     = (short*)d_ws;
    short* partial = (short*)((char*)d_ws + (size_t)BH * 8192 * sizeof(short));

    auto fits = [&](int n) {
        return (size_t)(n + 1) * BH * 8192 * sizeof(short) <= ws_size;
    };
    const int nc = fits(8) ? 8 : (fits(4) ? 4 : 2);

    lin_attn_pass1<<<dim3(nc, BH), dim3(256), 0, stream>>>(k, v, partial, S / nc);
    lin_attn_reduce<<<dim3(8, BH), dim3(256), 0, stream>>>(partial, Mtb, nc);
    lin_attn_pass2<<<dim3(16, BH), dim3(256), 0, stream>>>(q, mask, Mtb, out);
}